// Round 3
// baseline (1131.666 us; speedup 1.0000x reference)
//
#include <hip/hip_runtime.h>

#define B_TOT 32768
#define NF    64
#define NB    33
#define NSEG  32   // NB-1
#define E     64
#define RPB   16   // b-rows per block (kernel 2)
#define TBL_BYTES (NF * NSEG * (E / 2) * 16)   // 1 MB of float4 records

typedef float v4f __attribute__((ext_vector_type(4)));   // native vec for nontemporal

// ---------------- kernel 1: build interleaved {P,W} table ----------------
// tbl[f][j][e2] = {P[j][2e2], P[j][2e2+1], W[j][2e2], W[j][2e2+1]}
// P[j][e] = bias[e] + sum_{i<j} W[i][e]
__global__ __launch_bounds__(256) void build_table(
    const float* __restrict__ W, const float* __restrict__ bias,
    float4* __restrict__ tbl)
{
    __shared__ __align__(16) float sW[NSEG][E];   // 8 KB
    __shared__ __align__(16) float sP[NSEG][E];   // 8 KB
    const int f = blockIdx.x, tid = threadIdx.x;

    const float4* Wg  = reinterpret_cast<const float4*>(W + f * (NSEG * E));
    float4*       sW4 = reinterpret_cast<float4*>(&sW[0][0]);
    sW4[tid]       = Wg[tid];
    sW4[tid + 256] = Wg[tid + 256];
    __syncthreads();

    if (tid < E) {
        float acc = bias[f * E + tid];
        #pragma unroll
        for (int j = 0; j < NSEG; ++j) { sP[j][tid] = acc; acc += sW[j][tid]; }
    }
    __syncthreads();

    #pragma unroll
    for (int t = 0; t < 4; ++t) {
        const int rec = tid + t * 256;          // 0..1023
        const int j = rec >> 5, e2 = rec & 31;
        tbl[f * 1024 + rec] =
            make_float4(sP[j][2 * e2], sP[j][2 * e2 + 1],
                        sW[j][2 * e2], sW[j][2 * e2 + 1]);
    }
}

// ---------------- kernel 2: contiguous-output main kernel ----------------
__global__ __launch_bounds__(256) void pwl_main(
    const float* __restrict__ X,       // [B, NF]
    const float* __restrict__ bounds,  // [NF, NB]
    const float4* __restrict__ tbl,    // [NF][NSEG][E/2] records
    float* __restrict__ out)           // [B, NF*E]
{
    __shared__ float sB[NF][NB];       // 8.25 KB, stride 33 (odd -> conflict-free)
    __shared__ uint2 sJF[RPB][NF];     // 8 KB {j, frac-bits}

    const int tid = threadIdx.x;
    const int r0  = blockIdx.x * RPB;

    // stage all bounds (flat copy, coalesced)
    for (int i = tid; i < NF * NB; i += 256) sB[0][i] = bounds[i];

    // X: thread t -> row r = t>>4, float4 quad q4 = t&15 (covers f = 4q4..4q4+3)
    // wave's 64 float4 loads are fully contiguous (1 KB)
    const int rA = tid >> 4, q4 = tid & 15;
    const float4 x4 =
        reinterpret_cast<const float4*>(X)[(size_t)(r0 + rA) * (NF / 4) + q4];
    __syncthreads();

    // ---- phase A: bucket 4 x-values per thread ----
    {
        const float xs[4] = {x4.x, x4.y, x4.z, x4.w};
        #pragma unroll
        for (int cc = 0; cc < 4; ++cc) {
            const int   f = q4 * 4 + cc;
            const float x = xs[cc];
            int c = 0;
            #pragma unroll
            for (int i = 0; i < NB; ++i) c += (sB[f][i] <= x) ? 1 : 0;
            int j = c - 1;
            j = (j < 0) ? 0 : ((j > NSEG - 1) ? NSEG - 1 : j);
            const float lo = sB[f][j];
            const float hi = sB[f][j + 1];
            float fr = (x - lo) / (hi - lo);
            fr = fminf(fmaxf(fr, 0.0f), 1.0f);
            sJF[rA][f] = make_uint2((unsigned)j, __float_as_uint(fr));
        }
    }
    __syncthreads();

    // ---- phase B: thread t -> f = t>>2, e-block q = t&3 (e = 16q..16q+15) ----
    // Per iteration the wave stores 256 consecutive float4 = 4 KB contiguous.
    const int f = tid >> 2;
    const int q = tid & 3;
    const float4* tf = tbl + f * 1024 + q * 8;
    v4f* out4 = reinterpret_cast<v4f*>(out) +
                (size_t)r0 * (NF * E / 4) + f * 16 + q * 4;

    #pragma unroll 2
    for (int it = 0; it < RPB; ++it) {
        const uint2 jf = sJF[it][f];              // 16 addrs/wave, 16 banks: free
        const float fr = __uint_as_float(jf.y);
        const float4* __restrict__ rec = tf + jf.x * 32;   // 128 B/thread from L2
        v4f o[4];
        #pragma unroll
        for (int m = 0; m < 4; ++m) {
            const float4 a = rec[2 * m];
            const float4 b = rec[2 * m + 1];
            o[m][0] = fmaxf(fmaf(fr, a.z, a.x), 0.0f);
            o[m][1] = fmaxf(fmaf(fr, a.w, a.y), 0.0f);
            o[m][2] = fmaxf(fmaf(fr, b.z, b.x), 0.0f);
            o[m][3] = fmaxf(fmaf(fr, b.w, b.y), 0.0f);
        }
        #pragma unroll
        for (int m = 0; m < 4; ++m)
            __builtin_nontemporal_store(o[m], out4 + (size_t)it * (NF * E / 4) + m);
    }
}

// ---------------- fallback (round-1 kernel) if workspace too small ----------------
#define BPB 256
__global__ __launch_bounds__(256) void pwl_fallback(
    const float* __restrict__ X, const float* __restrict__ bounds,
    const float* __restrict__ W, const float* __restrict__ bias,
    float* __restrict__ out)
{
    __shared__ __align__(16) float4 sPW[NSEG][E / 2];
    __shared__ float sBounds[NB];
    __shared__ uint2 sJF[BPB];

    const int f   = blockIdx.x;
    const int tid = threadIdx.x;
    const int b0  = blockIdx.y * BPB;

    const float x = X[(size_t)(b0 + tid) * NF + f];
    float biasv = 0.0f;
    if (tid < E) biasv = bias[f * E + tid];

    {
        const float2* Wg   = reinterpret_cast<const float2*>(W + f * (NSEG * E));
        float*        flat = &sPW[0][0].x;
        #pragma unroll
        for (int t = 0; t < 4; ++t) {
            const int idx = tid + t * 256;
            const float2 w2 = Wg[idx];
            *reinterpret_cast<float2*>(flat + idx * 4 + 2) = w2;
        }
        if (tid < NB) sBounds[tid] = bounds[f * NB + tid];
    }
    __syncthreads();

    {
        int c = 0;
        #pragma unroll
        for (int i = 0; i < NB; ++i) c += (sBounds[i] <= x) ? 1 : 0;
        int j = c - 1;
        j = (j < 0) ? 0 : ((j > NSEG - 1) ? NSEG - 1 : j);
        const float lo = sBounds[j];
        const float hi = sBounds[j + 1];
        float fr = (x - lo) / (hi - lo);
        fr = fminf(fmaxf(fr, 0.0f), 1.0f);
        sJF[tid] = make_uint2((unsigned)j, __float_as_uint(fr));
    }

    if (tid < E) {
        const int e2 = tid >> 1;
        const int c  = tid & 1;
        float acc = biasv;
        float* flat = &sPW[0][0].x;
        #pragma unroll
        for (int i = 0; i < NSEG; ++i) {
            float* cell = flat + (i * 32 + e2) * 4;
            const float w = cell[2 + c];
            cell[c] = acc;
            acc += w;
        }
    }
    __syncthreads();

    const int lane  = tid & 63;
    const int wv    = tid >> 6;
    const int half  = lane >> 5;
    const int e2    = lane & 31;
    const int wbase = wv * 64;

    const float4* __restrict__ PW = &sPW[0][0];
    float2* outp = reinterpret_cast<float2*>(
        out + (size_t)(b0 + wbase + half) * (NF * E) + f * E + 2 * e2);

    #pragma unroll 8
    for (int it = 0; it < 32; ++it) {
        const uint2 jf = sJF[wbase + 2 * it + half];
        const int   j  = (int)jf.x;
        const float fr = __uint_as_float(jf.y);
        const float4 v = PW[j * 32 + e2];
        float2 r;
        r.x = fmaxf(fmaf(fr, v.z, v.x), 0.0f);
        r.y = fmaxf(fmaf(fr, v.w, v.y), 0.0f);
        *outp = r;
        outp += 4096;
    }
}

extern "C" void kernel_launch(void* const* d_in, const int* in_sizes, int n_in,
                              void* d_out, int out_size, void* d_ws, size_t ws_size,
                              hipStream_t stream) {
    const float* X      = (const float*)d_in[0];
    const float* bounds = (const float*)d_in[1];
    const float* W      = (const float*)d_in[2];
    const float* bias   = (const float*)d_in[3];
    float* out          = (float*)d_out;

    if (ws_size >= (size_t)TBL_BYTES && d_ws != nullptr) {
        float4* tbl = (float4*)d_ws;
        build_table<<<dim3(NF), dim3(256), 0, stream>>>(W, bias, tbl);
        pwl_main<<<dim3(B_TOT / RPB), dim3(256), 0, stream>>>(X, bounds, tbl, out);
    } else {
        dim3 grid(NF, B_TOT / BPB);
        pwl_fallback<<<grid, dim3(256), 0, stream>>>(X, bounds, W, bias, out);
    }
}